// Round 2
// baseline (745.476 us; speedup 1.0000x reference)
//
#include <hip/hip_runtime.h>
#include <hip/hip_bf16.h>

// B=4, C=384, H=W=56 (S=3136, padded 3200), NH=12, HD=32, WS=7, pad=3.
#define S_HW 3136
#define SP   3200
#define IMG_W 56
#define C_DIM 384
#define NH_DIM 12

typedef float f32x4 __attribute__((ext_vector_type(4)));
typedef short bf16x8 __attribute__((ext_vector_type(8)));

__device__ __forceinline__ void gld_lds16(const void* g, void* lds) {
    __builtin_amdgcn_global_load_lds(
        (const __attribute__((address_space(1))) void*)g,
        (__attribute__((address_space(3))) void*)lds, 16, 0, 0);
}

__device__ __forceinline__ void store_val(__hip_bfloat16* p, float v) { *p = __float2bfloat16(v); }
__device__ __forceinline__ void store_val(float* p, float v) { *p = v; }

// ---------------------------------------------------------------------------
// fp32 -> bf16 elementwise convert (weights)
// ---------------------------------------------------------------------------
__global__ __launch_bounds__(256) void convert_w_kernel(
    const float* __restrict__ in, __hip_bfloat16* __restrict__ out, int n)
{
    int i = blockIdx.x * 256 + threadIdx.x;
    if (i < n) out[i] = __float2bfloat16(in[i]);
}

// ---------------------------------------------------------------------------
// x [4][384][3136] f32  ->  x_t [4][3200][384] bf16 (transpose + convert)
// ---------------------------------------------------------------------------
__global__ __launch_bounds__(256) void transpose_convert_kernel(
    const float* __restrict__ x, __hip_bfloat16* __restrict__ xt)
{
    __shared__ float t[32][33];
    const int b = blockIdx.z;
    const int c0 = blockIdx.y * 32, s0 = blockIdx.x * 32;
    const int tx = threadIdx.x, ty = threadIdx.y;   // 32 x 8
    const float* xb = x + ((size_t)b * C_DIM + c0) * S_HW + s0;
    #pragma unroll
    for (int i = 0; i < 4; ++i)
        t[ty + i * 8][tx] = xb[(size_t)(ty + i * 8) * S_HW + tx];
    __syncthreads();
    __hip_bfloat16* xtb = xt + ((size_t)b * SP + s0) * C_DIM + c0;
    #pragma unroll
    for (int i = 0; i < 4; ++i)
        xtb[(size_t)(ty + i * 8) * C_DIM + tx] = __float2bfloat16(t[tx][ty + i * 8]);
}

// ---------------------------------------------------------------------------
// bf16 MFMA GEMM (m97 structure): Y[b][o][s] = sum_k A[o][k] * Bt[b][s][k]
// 128x128 tile, BK=32, 4 waves (2x2), 4x4 16x16x32 fragments per wave.
// O % 128 == 0, K % 32 == 0. Bt padded to SP rows; C-write guarded s < S_HW.
// Epilogue: +bias[o]; rows < qrows scaled by qscale.
// ---------------------------------------------------------------------------
template <typename OutT>
__global__ __launch_bounds__(256) void gemm_bf16_mfma(
    const __hip_bfloat16* __restrict__ A,    // [O][K]
    const __hip_bfloat16* __restrict__ Bt,   // [batch][SP][K]
    const float* __restrict__ bias,
    OutT* __restrict__ Y,                    // [batch][O][S_HW]
    int O, int K, float qscale, int qrows)
{
    __shared__ char smem[16384];
    char* As = smem;             // [128][32] bf16 linear
    char* Bs = smem + 8192;      // [128][32] bf16 linear

    const int b   = blockIdx.z;
    const int m0  = blockIdx.y * 128;
    const int n0  = blockIdx.x * 128;
    const int tid = threadIdx.x;
    const int w = tid >> 6, l = tid & 63;
    const int wr = w >> 1, wc = w & 1;

    const int srow = l >> 2;          // staging: row within 16-row chunk
    const int skk  = (l & 3) * 8;     // staging: k element offset

    const __hip_bfloat16* Bb = Bt + (size_t)b * SP * K;

    f32x4 acc[4][4];
    #pragma unroll
    for (int i = 0; i < 4; ++i)
        #pragma unroll
        for (int j = 0; j < 4; ++j) {
            f32x4 z = {0.f, 0.f, 0.f, 0.f};
            acc[i][j] = z;
        }

    const int frow = l & 15;
    const int fk   = (l >> 4) * 16;   // byte offset of 8-bf16 k-group

    for (int k0 = 0; k0 < K; k0 += 32) {
        #pragma unroll
        for (int j = 0; j < 2; ++j) {
            const int chunk = w * 2 + j;           // wave-uniform
            const int m = chunk * 16 + srow;
            gld_lds16(A  + (size_t)(m0 + m) * K + k0 + skk, As + chunk * 1024);
            gld_lds16(Bb + (size_t)(n0 + m) * K + k0 + skk, Bs + chunk * 1024);
        }
        __syncthreads();
        bf16x8 af[4], bfr[4];
        #pragma unroll
        for (int mi = 0; mi < 4; ++mi)
            af[mi] = *reinterpret_cast<const bf16x8*>(
                As + (wr * 64 + mi * 16 + frow) * 64 + fk);
        #pragma unroll
        for (int ni = 0; ni < 4; ++ni)
            bfr[ni] = *reinterpret_cast<const bf16x8*>(
                Bs + (wc * 64 + ni * 16 + frow) * 64 + fk);
        #pragma unroll
        for (int mi = 0; mi < 4; ++mi)
            #pragma unroll
            for (int ni = 0; ni < 4; ++ni)
                acc[mi][ni] = __builtin_amdgcn_mfma_f32_16x16x32_bf16(
                    af[mi], bfr[ni], acc[mi][ni], 0, 0, 0);
        __syncthreads();
    }

    // epilogue: C/D layout col=lane&15, row=(lane>>4)*4+reg  [m89]
    const int crow0 = (l >> 4) * 4;
    const int ccol  = l & 15;
    OutT* Yb = Y + (size_t)b * O * S_HW;
    #pragma unroll
    for (int ni = 0; ni < 4; ++ni) {
        const int col = n0 + wc * 64 + ni * 16 + ccol;
        if (col >= S_HW) continue;
        #pragma unroll
        for (int mi = 0; mi < 4; ++mi) {
            #pragma unroll
            for (int r = 0; r < 4; ++r) {
                const int row = m0 + wr * 64 + mi * 16 + crow0 + r;
                float v = acc[mi][ni][r] + bias[row];
                if (row < qrows) v *= qscale;
                store_val(&Yb[(size_t)row * S_HW + col], v);
            }
        }
    }
}

// ---------------------------------------------------------------------------
// Neighborhood attention: one thread per pixel per head (bf16 in/out).
// qkv layout [b][1152][S_HW] bf16 (q rows 0..383 pre-scaled, then k, then v).
// Output: attn_t [b][SP][384] bf16 (transposed for the proj GEMM).
// ---------------------------------------------------------------------------
__global__ __launch_bounds__(256) void na_attn_kernel(
    const __hip_bfloat16* __restrict__ qkv, const float* __restrict__ rel_bias,
    __hip_bfloat16* __restrict__ outt)
{
    const int blk  = blockIdx.x;          // b*NH*13 + nh*13 + tile
    const int tile = blk % 13;
    const int bn   = blk / 13;
    const int nh   = bn % NH_DIM;
    const int b    = bn / NH_DIM;
    const int s    = tile * 256 + threadIdx.x;
    if (s >= S_HW) return;
    const int h = s / IMG_W;
    const int w = s % IMG_W;

    const __hip_bfloat16* qb = qkv + ((size_t)b * 1152 + nh * 32) * S_HW;
    const __hip_bfloat16* kb = qb + (size_t)C_DIM * S_HW;
    const __hip_bfloat16* vb = qb + (size_t)(2 * C_DIM) * S_HW;

    float q[32];
    #pragma unroll
    for (int c = 0; c < 32; ++c) q[c] = __bfloat162float(qb[(size_t)c * S_HW + s]);

    float logits[49];
    #pragma unroll
    for (int di = 0; di < 7; ++di) {
        int y = h + di - 3; y = min(max(y, 0), 55);
        #pragma unroll
        for (int dj = 0; dj < 7; ++dj) {
            int x = w + dj - 3; x = min(max(x, 0), 55);
            const int ks = y * IMG_W + x;
            float dot = 0.f;
            #pragma unroll
            for (int c = 0; c < 32; ++c)
                dot = fmaf(q[c], __bfloat162float(kb[(size_t)c * S_HW + ks]), dot);
            logits[di * 7 + dj] = dot + rel_bias[(nh * 7 + di) * 7 + dj];
        }
    }

    float mx = logits[0];
    #pragma unroll
    for (int i = 1; i < 49; ++i) mx = fmaxf(mx, logits[i]);
    float sum = 0.f;
    #pragma unroll
    for (int i = 0; i < 49; ++i) { logits[i] = __expf(logits[i] - mx); sum += logits[i]; }
    const float inv = 1.f / sum;

    float o[32];
    #pragma unroll
    for (int c = 0; c < 32; ++c) o[c] = 0.f;
    #pragma unroll
    for (int di = 0; di < 7; ++di) {
        int y = h + di - 3; y = min(max(y, 0), 55);
        #pragma unroll
        for (int dj = 0; dj < 7; ++dj) {
            int x = w + dj - 3; x = min(max(x, 0), 55);
            const int ks = y * IMG_W + x;
            const float p = logits[di * 7 + dj];
            #pragma unroll
            for (int c = 0; c < 32; ++c)
                o[c] = fmaf(p, __bfloat162float(vb[(size_t)c * S_HW + ks]), o[c]);
        }
    }

    alignas(16) __hip_bfloat16 o16[32];
    #pragma unroll
    for (int c = 0; c < 32; ++c) o16[c] = __float2bfloat16(o[c] * inv);
    bf16x8* dst = reinterpret_cast<bf16x8*>(outt + ((size_t)b * SP + s) * C_DIM + nh * 32);
    const bf16x8* src = reinterpret_cast<const bf16x8*>(o16);
    #pragma unroll
    for (int i = 0; i < 4; ++i) dst[i] = src[i];
}

// ---------------------------------------------------------------------------
extern "C" void kernel_launch(void* const* d_in, const int* in_sizes, int n_in,
                              void* d_out, int out_size, void* d_ws, size_t ws_size,
                              hipStream_t stream) {
    const float* x        = (const float*)d_in[0];
    const float* w_qkv    = (const float*)d_in[1];
    const float* b_qkv    = (const float*)d_in[2];
    const float* w_proj   = (const float*)d_in[3];
    const float* b_proj   = (const float*)d_in[4];
    const float* rel_bias = (const float*)d_in[5];
    float* out = (float*)d_out;

    // Workspace (bf16): xt 9.8MB | wq 0.9MB | wp 0.3MB | qkv 28.9MB | att 9.8MB
    __hip_bfloat16* xt   = (__hip_bfloat16*)d_ws;
    __hip_bfloat16* wq   = xt + (size_t)4 * SP * C_DIM;
    __hip_bfloat16* wp   = wq + (size_t)1152 * C_DIM;
    __hip_bfloat16* qkvb = wp + (size_t)C_DIM * C_DIM;
    __hip_bfloat16* att  = qkvb + (size_t)4 * 1152 * S_HW;

    const float scale = 0.17677669529663687f;  // 32^-0.5

    convert_w_kernel<<<dim3((1152 * C_DIM + 255) / 256), 256, 0, stream>>>(
        w_qkv, wq, 1152 * C_DIM);
    convert_w_kernel<<<dim3((C_DIM * C_DIM + 255) / 256), 256, 0, stream>>>(
        w_proj, wp, C_DIM * C_DIM);
    transpose_convert_kernel<<<dim3(98, 12, 4), dim3(32, 8), 0, stream>>>(x, xt);

    // qkv projection: O=1152, K=384
    gemm_bf16_mfma<<<dim3(25, 9, 4), 256, 0, stream>>>(
        wq, xt, b_qkv, qkvb, 1152, C_DIM, scale, C_DIM);

    // attention
    na_attn_kernel<<<dim3(4 * NH_DIM * 13), 256, 0, stream>>>(qkvb, rel_bias, att);

    // output projection: O=384, K=384
    gemm_bf16_mfma<<<dim3(25, 3, 4), 256, 0, stream>>>(
        wp, att, b_proj, out, C_DIM, C_DIM, 1.f, 0);
}

// Round 3
// 259.304 us; speedup vs baseline: 2.8749x; 2.8749x over previous
//
#include <hip/hip_runtime.h>
#include <hip/hip_bf16.h>

// B=4, C=384, H=W=56 (S=3136, padded 3200), NH=12, HD=32, WS=7, pad=3.
#define S_HW 3136
#define SP   3200
#define IMG_W 56
#define C_DIM 384
#define NH_DIM 12
#define QKV_C 1152

typedef float f32x4 __attribute__((ext_vector_type(4)));
typedef short bf16x8 __attribute__((ext_vector_type(8)));

__device__ __forceinline__ void gld_lds16(const void* g, void* lds) {
    __builtin_amdgcn_global_load_lds(
        (const __attribute__((address_space(1))) void*)g,
        (__attribute__((address_space(3))) void*)lds, 16, 0, 0);
}

__device__ __forceinline__ float bf2f(short x) {
    return __uint_as_float(((unsigned int)(unsigned short)x) << 16);
}
__device__ __forceinline__ unsigned int f2bf_bits(float f) {
    unsigned int u = __float_as_uint(f);
    u += 0x7FFF + ((u >> 16) & 1);   // round-nearest-even
    return u >> 16;
}

// ---------------------------------------------------------------------------
// fp32 -> bf16 elementwise convert (weights)
// ---------------------------------------------------------------------------
__global__ __launch_bounds__(256) void convert_w_kernel(
    const float* __restrict__ in, __hip_bfloat16* __restrict__ out, int n)
{
    int i = blockIdx.x * 256 + threadIdx.x;
    if (i < n) out[i] = __float2bfloat16(in[i]);
}

// ---------------------------------------------------------------------------
// x [4][384][3136] f32  ->  x_t [4][3200][384] bf16 (transpose + convert)
// ---------------------------------------------------------------------------
__global__ __launch_bounds__(256) void transpose_convert_kernel(
    const float* __restrict__ x, __hip_bfloat16* __restrict__ xt)
{
    __shared__ float t[32][33];
    const int b = blockIdx.z;
    const int c0 = blockIdx.y * 32, s0 = blockIdx.x * 32;
    const int tx = threadIdx.x, ty = threadIdx.y;   // 32 x 8
    const float* xb = x + ((size_t)b * C_DIM + c0) * S_HW + s0;
    #pragma unroll
    for (int i = 0; i < 4; ++i)
        t[ty + i * 8][tx] = xb[(size_t)(ty + i * 8) * S_HW + tx];
    __syncthreads();
    __hip_bfloat16* xtb = xt + ((size_t)b * SP + s0) * C_DIM + c0;
    #pragma unroll
    for (int i = 0; i < 4; ++i)
        xtb[(size_t)(ty + i * 8) * C_DIM + tx] = __float2bfloat16(t[tx][ty + i * 8]);
}

// ---------------------------------------------------------------------------
// bf16 MFMA GEMM (m97 structure): acc[o][s] = sum_k A[o][k] * Bt[b][s][k]
// 128x128 tile, BK=32, 4 waves (2x2), 4x4 16x16x32 fragments per wave.
// TRANS_OUT=false: Y fp32 [b][O][S_HW]  (proj output)
// TRANS_OUT=true : Y bf16 [b][SP][O]    (qkv output, channel-contiguous)
// Epilogue: +bias[o]; rows < qrows scaled by qscale.
// ---------------------------------------------------------------------------
template <bool TRANS_OUT, typename OutT>
__global__ __launch_bounds__(256) void gemm_bf16_mfma(
    const __hip_bfloat16* __restrict__ A,    // [O][K]
    const __hip_bfloat16* __restrict__ Bt,   // [batch][SP][K]
    const float* __restrict__ bias,
    OutT* __restrict__ Y,
    int O, int K, float qscale, int qrows)
{
    __shared__ char smem[16384];
    char* As = smem;             // [128][32] bf16 linear
    char* Bs = smem + 8192;      // [128][32] bf16 linear

    const int b   = blockIdx.z;
    const int m0  = blockIdx.y * 128;
    const int n0  = blockIdx.x * 128;
    const int tid = threadIdx.x;
    const int w = tid >> 6, l = tid & 63;
    const int wr = w >> 1, wc = w & 1;

    const int srow = l >> 2;          // staging: row within 16-row chunk
    const int skk  = (l & 3) * 8;     // staging: k element offset

    const __hip_bfloat16* Bb = Bt + (size_t)b * SP * K;

    f32x4 acc[4][4];
    #pragma unroll
    for (int i = 0; i < 4; ++i)
        #pragma unroll
        for (int j = 0; j < 4; ++j) {
            f32x4 z = {0.f, 0.f, 0.f, 0.f};
            acc[i][j] = z;
        }

    const int frow = l & 15;
    const int fk   = (l >> 4) * 16;   // byte offset of 8-bf16 k-group

    for (int k0 = 0; k0 < K; k0 += 32) {
        #pragma unroll
        for (int j = 0; j < 2; ++j) {
            const int chunk = w * 2 + j;           // wave-uniform
            const int m = chunk * 16 + srow;
            gld_lds16(A  + (size_t)(m0 + m) * K + k0 + skk, As + chunk * 1024);
            gld_lds16(Bb + (size_t)(n0 + m) * K + k0 + skk, Bs + chunk * 1024);
        }
        __syncthreads();
        bf16x8 af[4], bfr[4];
        #pragma unroll
        for (int mi = 0; mi < 4; ++mi)
            af[mi] = *reinterpret_cast<const bf16x8*>(
                As + (wr * 64 + mi * 16 + frow) * 64 + fk);
        #pragma unroll
        for (int ni = 0; ni < 4; ++ni)
            bfr[ni] = *reinterpret_cast<const bf16x8*>(
                Bs + (wc * 64 + ni * 16 + frow) * 64 + fk);
        #pragma unroll
        for (int mi = 0; mi < 4; ++mi)
            #pragma unroll
            for (int ni = 0; ni < 4; ++ni)
                acc[mi][ni] = __builtin_amdgcn_mfma_f32_16x16x32_bf16(
                    af[mi], bfr[ni], acc[mi][ni], 0, 0, 0);
        __syncthreads();
    }

    // epilogue: C/D layout col=lane&15, row=(lane>>4)*4+reg  [m89]
    const int crow0 = (l >> 4) * 4;
    const int ccol  = l & 15;
    if (TRANS_OUT) {
        // Y[b][col][row] bf16; per (mi,ni) one 8B store of 4 consecutive rows
        __hip_bfloat16* Yb = (__hip_bfloat16*)Y + (size_t)b * SP * O;
        #pragma unroll
        for (int ni = 0; ni < 4; ++ni) {
            const int col = n0 + wc * 64 + ni * 16 + ccol;
            if (col >= S_HW) continue;
            #pragma unroll
            for (int mi = 0; mi < 4; ++mi) {
                const int row0 = m0 + wr * 64 + mi * 16 + crow0;
                const float sc = (row0 < qrows) ? qscale : 1.f;
                float v0 = (acc[mi][ni][0] + bias[row0 + 0]) * sc;
                float v1 = (acc[mi][ni][1] + bias[row0 + 1]) * sc;
                float v2 = (acc[mi][ni][2] + bias[row0 + 2]) * sc;
                float v3 = (acc[mi][ni][3] + bias[row0 + 3]) * sc;
                uint2 pk;
                pk.x = f2bf_bits(v0) | (f2bf_bits(v1) << 16);
                pk.y = f2bf_bits(v2) | (f2bf_bits(v3) << 16);
                *reinterpret_cast<uint2*>(&Yb[(size_t)col * O + row0]) = pk;
            }
        }
    } else {
        float* Yb = (float*)Y + (size_t)b * O * S_HW;
        #pragma unroll
        for (int ni = 0; ni < 4; ++ni) {
            const int col = n0 + wc * 64 + ni * 16 + ccol;
            if (col >= S_HW) continue;
            #pragma unroll
            for (int mi = 0; mi < 4; ++mi) {
                #pragma unroll
                for (int r = 0; r < 4; ++r) {
                    const int row = m0 + wr * 64 + mi * 16 + crow0 + r;
                    float v = acc[mi][ni][r] + bias[row];
                    if (row < qrows) v *= qscale;
                    Yb[(size_t)row * S_HW + col] = v;
                }
            }
        }
    }
}

// ---------------------------------------------------------------------------
// Neighborhood attention, channel-contiguous layout.
// qkvt [b][SP][1152] bf16: per pixel, ch 0..383 = q (pre-scaled),
// 384..767 = k, 768..1151 = v. Output att [b][SP][384] bf16.
// One thread per (pixel, head); all q/k/v accesses are 16B vector loads.
// ---------------------------------------------------------------------------
__global__ __launch_bounds__(256) void na_attn_kernel(
    const __hip_bfloat16* __restrict__ qkvt, const float* __restrict__ rel_bias,
    __hip_bfloat16* __restrict__ outt)
{
    const int blk  = blockIdx.x;          // b*NH*13 + nh*13 + tile
    const int tile = blk % 13;
    const int bn   = blk / 13;
    const int nh   = bn % NH_DIM;
    const int b    = bn / NH_DIM;
    const int s    = tile * 256 + threadIdx.x;
    if (s >= S_HW) return;
    const int h = s / IMG_W;
    const int w = s % IMG_W;

    const __hip_bfloat16* base = qkvt + (size_t)b * SP * QKV_C;
    const int co = nh * 32;

    float qf[32];
    {
        const bf16x8* qp = reinterpret_cast<const bf16x8*>(base + (size_t)s * QKV_C + co);
        #pragma unroll
        for (int g = 0; g < 4; ++g) {
            bf16x8 qg = qp[g];
            #pragma unroll
            for (int e = 0; e < 8; ++e) qf[g * 8 + e] = bf2f(qg[e]);
        }
    }

    float logits[49];
    #pragma unroll
    for (int di = 0; di < 7; ++di) {
        int y = h + di - 3; y = min(max(y, 0), 55);
        #pragma unroll
        for (int dj = 0; dj < 7; ++dj) {
            int x = w + dj - 3; x = min(max(x, 0), 55);
            const int ks = y * IMG_W + x;
            const bf16x8* kp = reinterpret_cast<const bf16x8*>(
                base + (size_t)ks * QKV_C + C_DIM + co);
            float dot = 0.f;
            #pragma unroll
            for (int g = 0; g < 4; ++g) {
                bf16x8 kg = kp[g];
                #pragma unroll
                for (int e = 0; e < 8; ++e)
                    dot = fmaf(qf[g * 8 + e], bf2f(kg[e]), dot);
            }
            logits[di * 7 + dj] = dot + rel_bias[(nh * 7 + di) * 7 + dj];
        }
    }

    float mx = logits[0];
    #pragma unroll
    for (int i = 1; i < 49; ++i) mx = fmaxf(mx, logits[i]);
    float sum = 0.f;
    #pragma unroll
    for (int i = 0; i < 49; ++i) { logits[i] = __expf(logits[i] - mx); sum += logits[i]; }
    const float inv = 1.f / sum;

    float o[32];
    #pragma unroll
    for (int c = 0; c < 32; ++c) o[c] = 0.f;
    #pragma unroll
    for (int di = 0; di < 7; ++di) {
        int y = h + di - 3; y = min(max(y, 0), 55);
        #pragma unroll
        for (int dj = 0; dj < 7; ++dj) {
            int x = w + dj - 3; x = min(max(x, 0), 55);
            const int ks = y * IMG_W + x;
            const bf16x8* vp = reinterpret_cast<const bf16x8*>(
                base + (size_t)ks * QKV_C + 2 * C_DIM + co);
            const float p = logits[di * 7 + dj];
            #pragma unroll
            for (int g = 0; g < 4; ++g) {
                bf16x8 vg = vp[g];
                #pragma unroll
                for (int e = 0; e < 8; ++e)
                    o[g * 8 + e] = fmaf(p, bf2f(vg[e]), o[g * 8 + e]);
            }
        }
    }

    uint4* dst = reinterpret_cast<uint4*>(outt + ((size_t)b * SP + s) * C_DIM + co);
    #pragma unroll
    for (int g = 0; g < 4; ++g) {
        uint4 pk;
        pk.x = f2bf_bits(o[g * 8 + 0] * inv) | (f2bf_bits(o[g * 8 + 1] * inv) << 16);
        pk.y = f2bf_bits(o[g * 8 + 2] * inv) | (f2bf_bits(o[g * 8 + 3] * inv) << 16);
        pk.z = f2bf_bits(o[g * 8 + 4] * inv) | (f2bf_bits(o[g * 8 + 5] * inv) << 16);
        pk.w = f2bf_bits(o[g * 8 + 6] * inv) | (f2bf_bits(o[g * 8 + 7] * inv) << 16);
        dst[g] = pk;
    }
}

// ---------------------------------------------------------------------------
extern "C" void kernel_launch(void* const* d_in, const int* in_sizes, int n_in,
                              void* d_out, int out_size, void* d_ws, size_t ws_size,
                              hipStream_t stream) {
    const float* x        = (const float*)d_in[0];
    const float* w_qkv    = (const float*)d_in[1];
    const float* b_qkv    = (const float*)d_in[2];
    const float* w_proj   = (const float*)d_in[3];
    const float* b_proj   = (const float*)d_in[4];
    const float* rel_bias = (const float*)d_in[5];
    float* out = (float*)d_out;

    // Workspace (bf16): xt 9.8MB | wq 0.9MB | wp 0.3MB | qkvt 29.5MB | att 9.8MB
    __hip_bfloat16* xt   = (__hip_bfloat16*)d_ws;
    __hip_bfloat16* wq   = xt + (size_t)4 * SP * C_DIM;
    __hip_bfloat16* wp   = wq + (size_t)QKV_C * C_DIM;
    __hip_bfloat16* qkvt = wp + (size_t)C_DIM * C_DIM;
    __hip_bfloat16* att  = qkvt + (size_t)4 * SP * QKV_C;

    const float scale = 0.17677669529663687f;  // 32^-0.5

    convert_w_kernel<<<dim3((QKV_C * C_DIM + 255) / 256), 256, 0, stream>>>(
        w_qkv, wq, QKV_C * C_DIM);
    convert_w_kernel<<<dim3((C_DIM * C_DIM + 255) / 256), 256, 0, stream>>>(
        w_proj, wp, C_DIM * C_DIM);
    transpose_convert_kernel<<<dim3(98, 12, 4), dim3(32, 8), 0, stream>>>(x, xt);

    // qkv projection: O=1152, K=384, transposed bf16 output [b][SP][1152]
    gemm_bf16_mfma<true, __hip_bfloat16><<<dim3(25, 9, 4), 256, 0, stream>>>(
        wq, xt, b_qkv, qkvt, QKV_C, C_DIM, scale, C_DIM);

    // attention
    na_attn_kernel<<<dim3(4 * NH_DIM * 13), 256, 0, stream>>>(qkvt, rel_bias, att);

    // output projection: O=384, K=384, fp32 output [b][384][S_HW]
    gemm_bf16_mfma<false, float><<<dim3(25, 3, 4), 256, 0, stream>>>(
        wp, att, b_proj, out, C_DIM, C_DIM, 1.f, 0);
}

// Round 4
// 112.327 us; speedup vs baseline: 6.6367x; 2.3085x over previous
//
#include <hip/hip_runtime.h>
#include <hip/hip_bf16.h>

// B=4, C=384, H=W=56 (S=3136, padded 3200), NH=12, HD=32, WS=7, pad=3.
#define S_HW 3136
#define SP   3200
#define IMG_W 56
#define C_DIM 384
#define NH_DIM 12
#define QKV_C 1152

// attention tiling
#define TB 16              // tile is TB x TB pixels
#define HALO 22            // TB + 6
#define NPX 484            // HALO*HALO
#define PLANE_B 3872       // NPX * 8 bytes per ch-quad plane

typedef float f32x4 __attribute__((ext_vector_type(4)));
typedef float f32x2 __attribute__((ext_vector_type(2)));
typedef short bf16x8 __attribute__((ext_vector_type(8)));

__device__ __forceinline__ void gld_lds16(const void* g, void* lds) {
    __builtin_amdgcn_global_load_lds(
        (const __attribute__((address_space(1))) void*)g,
        (__attribute__((address_space(3))) void*)lds, 16, 0, 0);
}

__device__ __forceinline__ float u2f(unsigned int u) { return __uint_as_float(u); }
__device__ __forceinline__ unsigned int f2bf_bits(float f) {
    unsigned int u = __float_as_uint(f);
    u += 0x7FFF + ((u >> 16) & 1);   // round-nearest-even
    return u >> 16;
}

// ---------------------------------------------------------------------------
__global__ __launch_bounds__(256) void convert_w_kernel(
    const float* __restrict__ in, __hip_bfloat16* __restrict__ out, int n)
{
    int i = blockIdx.x * 256 + threadIdx.x;
    if (i < n) out[i] = __float2bfloat16(in[i]);
}

// ---------------------------------------------------------------------------
// x [4][384][3136] f32  ->  x_t [4][3200][384] bf16 (transpose + convert)
// ---------------------------------------------------------------------------
__global__ __launch_bounds__(256) void transpose_convert_kernel(
    const float* __restrict__ x, __hip_bfloat16* __restrict__ xt)
{
    __shared__ float t[32][33];
    const int b = blockIdx.z;
    const int c0 = blockIdx.y * 32, s0 = blockIdx.x * 32;
    const int tx = threadIdx.x, ty = threadIdx.y;   // 32 x 8
    const float* xb = x + ((size_t)b * C_DIM + c0) * S_HW + s0;
    #pragma unroll
    for (int i = 0; i < 4; ++i)
        t[ty + i * 8][tx] = xb[(size_t)(ty + i * 8) * S_HW + tx];
    __syncthreads();
    __hip_bfloat16* xtb = xt + ((size_t)b * SP + s0) * C_DIM + c0;
    #pragma unroll
    for (int i = 0; i < 4; ++i)
        xtb[(size_t)(ty + i * 8) * C_DIM + tx] = __float2bfloat16(t[tx][ty + i * 8]);
}

// ---------------------------------------------------------------------------
// bf16 MFMA GEMM (m97 structure) — unchanged from round 3.
// ---------------------------------------------------------------------------
template <bool TRANS_OUT, typename OutT>
__global__ __launch_bounds__(256) void gemm_bf16_mfma(
    const __hip_bfloat16* __restrict__ A,    // [O][K]
    const __hip_bfloat16* __restrict__ Bt,   // [batch][SP][K]
    const float* __restrict__ bias,
    OutT* __restrict__ Y,
    int O, int K, float qscale, int qrows)
{
    __shared__ char smem[16384];
    char* As = smem;
    char* Bs = smem + 8192;

    const int b   = blockIdx.z;
    const int m0  = blockIdx.y * 128;
    const int n0  = blockIdx.x * 128;
    const int tid = threadIdx.x;
    const int w = tid >> 6, l = tid & 63;
    const int wr = w >> 1, wc = w & 1;

    const int srow = l >> 2;
    const int skk  = (l & 3) * 8;

    const __hip_bfloat16* Bb = Bt + (size_t)b * SP * K;

    f32x4 acc[4][4];
    #pragma unroll
    for (int i = 0; i < 4; ++i)
        #pragma unroll
        for (int j = 0; j < 4; ++j) {
            f32x4 z = {0.f, 0.f, 0.f, 0.f};
            acc[i][j] = z;
        }

    const int frow = l & 15;
    const int fk   = (l >> 4) * 16;

    for (int k0 = 0; k0 < K; k0 += 32) {
        #pragma unroll
        for (int j = 0; j < 2; ++j) {
            const int chunk = w * 2 + j;
            const int m = chunk * 16 + srow;
            gld_lds16(A  + (size_t)(m0 + m) * K + k0 + skk, As + chunk * 1024);
            gld_lds16(Bb + (size_t)(n0 + m) * K + k0 + skk, Bs + chunk * 1024);
        }
        __syncthreads();
        bf16x8 af[4], bfr[4];
        #pragma unroll
        for (int mi = 0; mi < 4; ++mi)
            af[mi] = *reinterpret_cast<const bf16x8*>(
                As + (wr * 64 + mi * 16 + frow) * 64 + fk);
        #pragma unroll
        for (int ni = 0; ni < 4; ++ni)
            bfr[ni] = *reinterpret_cast<const bf16x8*>(
                Bs + (wc * 64 + ni * 16 + frow) * 64 + fk);
        #pragma unroll
        for (int mi = 0; mi < 4; ++mi)
            #pragma unroll
            for (int ni = 0; ni < 4; ++ni)
                acc[mi][ni] = __builtin_amdgcn_mfma_f32_16x16x32_bf16(
                    af[mi], bfr[ni], acc[mi][ni], 0, 0, 0);
        __syncthreads();
    }

    const int crow0 = (l >> 4) * 4;
    const int ccol  = l & 15;
    if (TRANS_OUT) {
        __hip_bfloat16* Yb = (__hip_bfloat16*)Y + (size_t)b * SP * O;
        #pragma unroll
        for (int ni = 0; ni < 4; ++ni) {
            const int col = n0 + wc * 64 + ni * 16 + ccol;
            if (col >= S_HW) continue;
            #pragma unroll
            for (int mi = 0; mi < 4; ++mi) {
                const int row0 = m0 + wr * 64 + mi * 16 + crow0;
                const float sc = (row0 < qrows) ? qscale : 1.f;
                float v0 = (acc[mi][ni][0] + bias[row0 + 0]) * sc;
                float v1 = (acc[mi][ni][1] + bias[row0 + 1]) * sc;
                float v2 = (acc[mi][ni][2] + bias[row0 + 2]) * sc;
                float v3 = (acc[mi][ni][3] + bias[row0 + 3]) * sc;
                uint2 pk;
                pk.x = f2bf_bits(v0) | (f2bf_bits(v1) << 16);
                pk.y = f2bf_bits(v2) | (f2bf_bits(v3) << 16);
                *reinterpret_cast<uint2*>(&Yb[(size_t)col * O + row0]) = pk;
            }
        }
    } else {
        float* Yb = (float*)Y + (size_t)b * O * S_HW;
        #pragma unroll
        for (int ni = 0; ni < 4; ++ni) {
            const int col = n0 + wc * 64 + ni * 16 + ccol;
            if (col >= S_HW) continue;
            #pragma unroll
            for (int mi = 0; mi < 4; ++mi) {
                #pragma unroll
                for (int r = 0; r < 4; ++r) {
                    const int row = m0 + wr * 64 + mi * 16 + crow0 + r;
                    float v = acc[mi][ni][r] + bias[row];
                    if (row < qrows) v *= qscale;
                    Yb[(size_t)row * S_HW + col] = v;
                }
            }
        }
    }
}

// ---------------------------------------------------------------------------
// Neighborhood attention, LDS-staged halo.
// Block = 16x16 pixel tile x one (b, nh). Halo 22x22 staged in LDS as
// [ch_quad(8)][px(484)] 8-byte entries -> conflict-free stride-8B ds_read_b64.
// K staged first (QK phase), then V overwrites the same buffer (PV phase).
// ---------------------------------------------------------------------------
__global__ __launch_bounds__(256, 4) void na_attn_kernel(
    const __hip_bfloat16* __restrict__ qkvt, const float* __restrict__ rel_bias,
    __hip_bfloat16* __restrict__ outt)
{
    __shared__ alignas(16) char halo[8 * PLANE_B];   // 31 KB

    const int blk  = blockIdx.x;          // b*NH*16 + nh*16 + tile
    const int tile = blk & 15;
    const int bn   = blk >> 4;
    const int nh   = bn % NH_DIM;
    const int b    = bn / NH_DIM;
    const int th0  = (tile >> 2) * TB;
    const int tw0  = (tile & 3) * TB;

    const int tid = threadIdx.x;
    const int ty = tid >> 4, tx = tid & 15;
    const int h = th0 + ty, w = tw0 + tx;
    const bool valid = (h < 56) && (w < 56);
    const int s = h * IMG_W + w;

    const __hip_bfloat16* base = qkvt + (size_t)b * SP * QKV_C;
    const int co = nh * 32;

    // ---- stage K halo: 484 px * 4 groups of 16B = 1936 loads
    #pragma unroll
    for (int i = 0; i < 8; ++i) {
        const int idx = tid + i * 256;
        if (idx < NPX * 4) {
            const int px = idx >> 2, g = idx & 3;
            const int hy = px / HALO, hx = px - hy * HALO;
            const int y = min(max(th0 - 3 + hy, 0), 55);
            const int x = min(max(tw0 - 3 + hx, 0), 55);
            const uint4 v = *reinterpret_cast<const uint4*>(
                base + (size_t)(y * IMG_W + x) * QKV_C + C_DIM + co + g * 8);
            uint2 lo; lo.x = v.x; lo.y = v.y;
            uint2 hi; hi.x = v.z; hi.y = v.w;
            *reinterpret_cast<uint2*>(&halo[(2 * g + 0) * PLANE_B + px * 8]) = lo;
            *reinterpret_cast<uint2*>(&halo[(2 * g + 1) * PLANE_B + px * 8]) = hi;
        }
    }

    // ---- own q, unpacked to f32x2 pairs (pair p = ch 2p, 2p+1)
    f32x2 qf2[16];
    if (valid) {
        const uint4* qp = reinterpret_cast<const uint4*>(base + (size_t)s * QKV_C + co);
        #pragma unroll
        for (int g = 0; g < 4; ++g) {
            uint4 qg = qp[g];
            qf2[4 * g + 0] = f32x2{u2f(qg.x << 16), u2f(qg.x & 0xFFFF0000u)};
            qf2[4 * g + 1] = f32x2{u2f(qg.y << 16), u2f(qg.y & 0xFFFF0000u)};
            qf2[4 * g + 2] = f32x2{u2f(qg.z << 16), u2f(qg.z & 0xFFFF0000u)};
            qf2[4 * g + 3] = f32x2{u2f(qg.w << 16), u2f(qg.w & 0xFFFF0000u)};
        }
    }
    __syncthreads();

    // ---- QK: 49 dots from LDS
    float logits[49];
    if (valid) {
        #pragma unroll
        for (int di = 0; di < 7; ++di) {
            #pragma unroll
            for (int dj = 0; dj < 7; ++dj) {
                const int hp = (ty + di) * HALO + (tx + dj);
                const char* hb = halo + hp * 8;
                f32x2 acc = {0.f, 0.f};
                #pragma unroll
                for (int pl = 0; pl < 8; ++pl) {
                    uint2 kk = *reinterpret_cast<const uint2*>(hb + pl * PLANE_B);
                    f32x2 k0 = f32x2{u2f(kk.x << 16), u2f(kk.x & 0xFFFF0000u)};
                    f32x2 k1 = f32x2{u2f(kk.y << 16), u2f(kk.y & 0xFFFF0000u)};
                    acc += qf2[2 * pl] * k0;
                    acc += qf2[2 * pl + 1] * k1;
                }
                logits[di * 7 + dj] = acc.x + acc.y + rel_bias[(nh * 7 + di) * 7 + dj];
            }
        }
    }
    __syncthreads();    // all K reads done before V overwrites

    // ---- stage V halo into the same buffer
    #pragma unroll
    for (int i = 0; i < 8; ++i) {
        const int idx = tid + i * 256;
        if (idx < NPX * 4) {
            const int px = idx >> 2, g = idx & 3;
            const int hy = px / HALO, hx = px - hy * HALO;
            const int y = min(max(th0 - 3 + hy, 0), 55);
            const int x = min(max(tw0 - 3 + hx, 0), 55);
            const uint4 v = *reinterpret_cast<const uint4*>(
                base + (size_t)(y * IMG_W + x) * QKV_C + 2 * C_DIM + co + g * 8);
            uint2 lo; lo.x = v.x; lo.y = v.y;
            uint2 hi; hi.x = v.z; hi.y = v.w;
            *reinterpret_cast<uint2*>(&halo[(2 * g + 0) * PLANE_B + px * 8]) = lo;
            *reinterpret_cast<uint2*>(&halo[(2 * g + 1) * PLANE_B + px * 8]) = hi;
        }
    }

    // ---- softmax (overlaps V staging latency); pack p to bf16 pairs
    unsigned int ppk[25];
    float inv = 0.f;
    if (valid) {
        float mx = logits[0];
        #pragma unroll
        for (int i = 1; i < 49; ++i) mx = fmaxf(mx, logits[i]);
        float sum = 0.f;
        #pragma unroll
        for (int i = 0; i < 24; ++i) {
            float e0 = __expf(logits[2 * i] - mx);
            float e1 = __expf(logits[2 * i + 1] - mx);
            sum += e0 + e1;
            ppk[i] = f2bf_bits(e0) << 16 | f2bf_bits(e1);   // hi=e0, lo=e1 (see PV)
        }
        {
            float e0 = __expf(logits[48] - mx);
            sum += e0;
            ppk[24] = f2bf_bits(e0) << 16;
        }
        inv = 1.f / sum;
    }
    __syncthreads();

    // ---- PV: accumulate o from LDS
    if (valid) {
        f32x2 o2[16];
        #pragma unroll
        for (int p = 0; p < 16; ++p) o2[p] = f32x2{0.f, 0.f};

        #pragma unroll
        for (int n = 0; n < 49; ++n) {
            const unsigned int pu = ppk[n >> 1];
            const float pv = (n & 1) ? u2f(pu << 16) : u2f(pu & 0xFFFF0000u);
            const int di = n / 7, dj = n % 7;
            const int hp = (ty + di) * HALO + (tx + dj);
            const char* hb = halo + hp * 8;
            const f32x2 pp = f32x2{pv, pv};
            #pragma unroll
            for (int pl = 0; pl < 8; ++pl) {
                uint2 vv = *reinterpret_cast<const uint2*>(hb + pl * PLANE_B);
                f32x2 v0 = f32x2{u2f(vv.x << 16), u2f(vv.x & 0xFFFF0000u)};
                f32x2 v1 = f32x2{u2f(vv.y << 16), u2f(vv.y & 0xFFFF0000u)};
                o2[2 * pl]     += pp * v0;
                o2[2 * pl + 1] += pp * v1;
            }
        }

        uint4* dst = reinterpret_cast<uint4*>(outt + ((size_t)b * SP + s) * C_DIM + co);
        #pragma unroll
        for (int g = 0; g < 4; ++g) {
            uint4 pk;
            pk.x = f2bf_bits(o2[4 * g + 0].x * inv) | (f2bf_bits(o2[4 * g + 0].y * inv) << 16);
            pk.y = f2bf_bits(o2[4 * g + 1].x * inv) | (f2bf_bits(o2[4 * g + 1].y * inv) << 16);
            pk.z = f2bf_bits(o2[4 * g + 2].x * inv) | (f2bf_bits(o2[4 * g + 2].y * inv) << 16);
            pk.w = f2bf_bits(o2[4 * g + 3].x * inv) | (f2bf_bits(o2[4 * g + 3].y * inv) << 16);
            dst[g] = pk;
        }
    }
}

// ---------------------------------------------------------------------------
extern "C" void kernel_launch(void* const* d_in, const int* in_sizes, int n_in,
                              void* d_out, int out_size, void* d_ws, size_t ws_size,
                              hipStream_t stream) {
    const float* x        = (const float*)d_in[0];
    const float* w_qkv    = (const float*)d_in[1];
    const float* b_qkv    = (const float*)d_in[2];
    const float* w_proj   = (const float*)d_in[3];
    const float* b_proj   = (const float*)d_in[4];
    const float* rel_bias = (const float*)d_in[5];
    float* out = (float*)d_out;

    __hip_bfloat16* xt   = (__hip_bfloat16*)d_ws;
    __hip_bfloat16* wq   = xt + (size_t)4 * SP * C_DIM;
    __hip_bfloat16* wp   = wq + (size_t)QKV_C * C_DIM;
    __hip_bfloat16* qkvt = wp + (size_t)C_DIM * C_DIM;
    __hip_bfloat16* att  = qkvt + (size_t)4 * SP * QKV_C;

    const float scale = 0.17677669529663687f;  // 32^-0.5

    convert_w_kernel<<<dim3((QKV_C * C_DIM + 255) / 256), 256, 0, stream>>>(
        w_qkv, wq, QKV_C * C_DIM);
    convert_w_kernel<<<dim3((C_DIM * C_DIM + 255) / 256), 256, 0, stream>>>(
        w_proj, wp, C_DIM * C_DIM);
    transpose_convert_kernel<<<dim3(98, 12, 4), dim3(32, 8), 0, stream>>>(x, xt);

    // qkv projection: O=1152, K=384, transposed bf16 output [b][SP][1152]
    gemm_bf16_mfma<true, __hip_bfloat16><<<dim3(25, 9, 4), 256, 0, stream>>>(
        wq, xt, b_qkv, qkvt, QKV_C, C_DIM, scale, C_DIM);

    // attention: 4 b * 12 heads * 16 tiles (4x4 of 16x16 px)
    na_attn_kernel<<<dim3(4 * NH_DIM * 16), 256, 0, stream>>>(qkvt, rel_bias, att);

    // output projection: O=384, K=384, fp32 output [b][384][S_HW]
    gemm_bf16_mfma<false, float><<<dim3(25, 3, 4), 256, 0, stream>>>(
        wp, att, b_proj, out, C_DIM, C_DIM, 1.f, 0);
}

// Round 5
// 101.522 us; speedup vs baseline: 7.3430x; 1.1064x over previous
//
#include <hip/hip_runtime.h>
#include <hip/hip_bf16.h>
#include <hip/hip_fp16.h>

// B=4, C=384, H=W=56 (S=3136, padded 3200), NH=12, HD=32, WS=7, pad=3.
#define S_HW 3136
#define SP   3200
#define IMG_W 56
#define C_DIM 384
#define NH_DIM 12
#define QKV_C 1152
#define F16_ROWS 768       // qkv rows [0,768) stored f16 (q,k); v rows bf16

// attention tiling
#define TB 16              // tile is TB x TB pixels
#define HALO 22            // TB + 6
#define NPX 484            // HALO*HALO
#define PLANE_B 3880       // NPX*8 rounded up (+8) to stagger plane banks

typedef float f32x4 __attribute__((ext_vector_type(4)));
typedef float f32x2 __attribute__((ext_vector_type(2)));
typedef short bf16x8 __attribute__((ext_vector_type(8)));
typedef _Float16 f16x2 __attribute__((ext_vector_type(2)));

__device__ __forceinline__ void gld_lds16(const void* g, void* lds) {
    __builtin_amdgcn_global_load_lds(
        (const __attribute__((address_space(1))) void*)g,
        (__attribute__((address_space(3))) void*)lds, 16, 0, 0);
}

__device__ __forceinline__ float u2f(unsigned int u) { return __uint_as_float(u); }
__device__ __forceinline__ unsigned int f2bf_bits(float f) {
    unsigned int u = __float_as_uint(f);
    u += 0x7FFF + ((u >> 16) & 1);   // round-nearest-even
    return u >> 16;
}
__device__ __forceinline__ unsigned int f2h_bits(float f) {
    return (unsigned int)__half_as_ushort(__float2half(f));
}

// ---------------------------------------------------------------------------
// fp32 -> bf16 convert for both weight tensors in one launch
// ---------------------------------------------------------------------------
__global__ __launch_bounds__(256) void convert_w2_kernel(
    const float* __restrict__ a, int na, __hip_bfloat16* __restrict__ oa,
    const float* __restrict__ b, int nb, __hip_bfloat16* __restrict__ ob)
{
    int i = blockIdx.x * 256 + threadIdx.x;
    if (i < na) oa[i] = __float2bfloat16(a[i]);
    else if (i < na + nb) ob[i - na] = __float2bfloat16(b[i - na]);
}

// ---------------------------------------------------------------------------
// x [4][384][3136] f32  ->  x_t [4][3200][384] bf16 (transpose + convert)
// 32x32 tile; 8B-granular loads and stores.
// ---------------------------------------------------------------------------
__global__ __launch_bounds__(256) void transpose_convert_kernel(
    const float* __restrict__ x, __hip_bfloat16* __restrict__ xt)
{
    __shared__ float t[32][33];
    const int b = blockIdx.z;
    const int c0 = blockIdx.y * 32, s0 = blockIdx.x * 32;
    const int tid = threadIdx.x;

    // load: thread -> x[c0 + tid/8][s0 + (tid%8)*4 ..+3]
    const int lc = tid >> 3, ls = (tid & 7) * 4;
    float4 v = *reinterpret_cast<const float4*>(
        &x[((size_t)b * C_DIM + c0 + lc) * S_HW + s0 + ls]);
    t[lc][ls + 0] = v.x; t[lc][ls + 1] = v.y;
    t[lc][ls + 2] = v.z; t[lc][ls + 3] = v.w;
    __syncthreads();

    // store: thread -> xt[s0 + tid/8][c0 + (tid%8)*4 ..+3]  (8B packed)
    const int ws = tid >> 3, wc = (tid & 7) * 4;
    uint2 pk;
    pk.x = f2bf_bits(t[wc + 0][ws]) | (f2bf_bits(t[wc + 1][ws]) << 16);
    pk.y = f2bf_bits(t[wc + 2][ws]) | (f2bf_bits(t[wc + 3][ws]) << 16);
    *reinterpret_cast<uint2*>(
        &xt[((size_t)b * SP + s0 + ws) * C_DIM + c0 + wc]) = pk;
}

// ---------------------------------------------------------------------------
// bf16 MFMA GEMM (m97 structure).
// TRANS_OUT=true : Y [b][SP][O], rows < F16_ROWS stored f16, else bf16.
// TRANS_OUT=false: Y fp32 [b][O][S_HW].
// ---------------------------------------------------------------------------
template <bool TRANS_OUT, typename OutT>
__global__ __launch_bounds__(256) void gemm_bf16_mfma(
    const __hip_bfloat16* __restrict__ A,    // [O][K]
    const __hip_bfloat16* __restrict__ Bt,   // [batch][SP][K]
    const float* __restrict__ bias,
    OutT* __restrict__ Y,
    int O, int K, float qscale, int qrows, int f16rows)
{
    __shared__ char smem[16384];
    char* As = smem;
    char* Bs = smem + 8192;

    const int b   = blockIdx.z;
    const int m0  = blockIdx.y * 128;
    const int n0  = blockIdx.x * 128;
    const int tid = threadIdx.x;
    const int w = tid >> 6, l = tid & 63;
    const int wr = w >> 1, wc = w & 1;

    const int srow = l >> 2;
    const int skk  = (l & 3) * 8;

    const __hip_bfloat16* Bb = Bt + (size_t)b * SP * K;

    f32x4 acc[4][4];
    #pragma unroll
    for (int i = 0; i < 4; ++i)
        #pragma unroll
        for (int j = 0; j < 4; ++j) {
            f32x4 z = {0.f, 0.f, 0.f, 0.f};
            acc[i][j] = z;
        }

    const int frow = l & 15;
    const int fk   = (l >> 4) * 16;

    for (int k0 = 0; k0 < K; k0 += 32) {
        #pragma unroll
        for (int j = 0; j < 2; ++j) {
            const int chunk = w * 2 + j;
            const int m = chunk * 16 + srow;
            gld_lds16(A  + (size_t)(m0 + m) * K + k0 + skk, As + chunk * 1024);
            gld_lds16(Bb + (size_t)(n0 + m) * K + k0 + skk, Bs + chunk * 1024);
        }
        __syncthreads();
        bf16x8 af[4], bfr[4];
        #pragma unroll
        for (int mi = 0; mi < 4; ++mi)
            af[mi] = *reinterpret_cast<const bf16x8*>(
                As + (wr * 64 + mi * 16 + frow) * 64 + fk);
        #pragma unroll
        for (int ni = 0; ni < 4; ++ni)
            bfr[ni] = *reinterpret_cast<const bf16x8*>(
                Bs + (wc * 64 + ni * 16 + frow) * 64 + fk);
        #pragma unroll
        for (int mi = 0; mi < 4; ++mi)
            #pragma unroll
            for (int ni = 0; ni < 4; ++ni)
                acc[mi][ni] = __builtin_amdgcn_mfma_f32_16x16x32_bf16(
                    af[mi], bfr[ni], acc[mi][ni], 0, 0, 0);
        __syncthreads();
    }

    const int crow0 = (l >> 4) * 4;
    const int ccol  = l & 15;
    if (TRANS_OUT) {
        __hip_bfloat16* Yb = (__hip_bfloat16*)Y + (size_t)b * SP * O;
        #pragma unroll
        for (int ni = 0; ni < 4; ++ni) {
            const int col = n0 + wc * 64 + ni * 16 + ccol;
            if (col >= S_HW) continue;
            #pragma unroll
            for (int mi = 0; mi < 4; ++mi) {
                const int row0 = m0 + wr * 64 + mi * 16 + crow0;
                const float sc = (row0 < qrows) ? qscale : 1.f;
                float v0 = (acc[mi][ni][0] + bias[row0 + 0]) * sc;
                float v1 = (acc[mi][ni][1] + bias[row0 + 1]) * sc;
                float v2 = (acc[mi][ni][2] + bias[row0 + 2]) * sc;
                float v3 = (acc[mi][ni][3] + bias[row0 + 3]) * sc;
                uint2 pk;
                if (row0 < f16rows) {   // q,k rows -> f16
                    pk.x = f2h_bits(v0) | (f2h_bits(v1) << 16);
                    pk.y = f2h_bits(v2) | (f2h_bits(v3) << 16);
                } else {                // v rows -> bf16
                    pk.x = f2bf_bits(v0) | (f2bf_bits(v1) << 16);
                    pk.y = f2bf_bits(v2) | (f2bf_bits(v3) << 16);
                }
                *reinterpret_cast<uint2*>(&Yb[(size_t)col * O + row0]) = pk;
            }
        }
    } else {
        float* Yb = (float*)Y + (size_t)b * O * S_HW;
        #pragma unroll
        for (int ni = 0; ni < 4; ++ni) {
            const int col = n0 + wc * 64 + ni * 16 + ccol;
            if (col >= S_HW) continue;
            #pragma unroll
            for (int mi = 0; mi < 4; ++mi) {
                #pragma unroll
                for (int r = 0; r < 4; ++r) {
                    const int row = m0 + wr * 64 + mi * 16 + crow0 + r;
                    float v = acc[mi][ni][r] + bias[row];
                    if (row < qrows) v *= qscale;
                    Yb[(size_t)row * S_HW + col] = v;
                }
            }
        }
    }
}

// ---------------------------------------------------------------------------
// Neighborhood attention, LDS-staged halo. q/k are f16 (dot2 path), v is bf16.
// ---------------------------------------------------------------------------
__global__ __launch_bounds__(256, 4) void na_attn_kernel(
    const __hip_bfloat16* __restrict__ qkvt, const float* __restrict__ rel_bias,
    __hip_bfloat16* __restrict__ outt)
{
    __shared__ alignas(16) char halo[8 * PLANE_B];   // ~31 KB

    const int blk  = blockIdx.x;          // b*NH*16 + nh*16 + tile
    const int tile = blk & 15;
    const int bn   = blk >> 4;
    const int nh   = bn % NH_DIM;
    const int b    = bn / NH_DIM;
    const int th0  = (tile >> 2) * TB;
    const int tw0  = (tile & 3) * TB;

    const int tid = threadIdx.x;
    const int ty = tid >> 4, tx = tid & 15;
    const int h = th0 + ty, w = tw0 + tx;
    const bool valid = (h < 56) && (w < 56);
    const int s = h * IMG_W + w;

    const __hip_bfloat16* base = qkvt + (size_t)b * SP * QKV_C;
    const int co = nh * 32;

    // ---- stage K halo (f16 bits; staging is bit-agnostic)
    #pragma unroll
    for (int i = 0; i < 8; ++i) {
        const int idx = tid + i * 256;
        if (idx < NPX * 4) {
            const int px = idx >> 2, g = idx & 3;
            const int hy = px / HALO, hx = px - hy * HALO;
            const int y = min(max(th0 - 3 + hy, 0), 55);
            const int x = min(max(tw0 - 3 + hx, 0), 55);
            const uint4 v = *reinterpret_cast<const uint4*>(
                base + (size_t)(y * IMG_W + x) * QKV_C + C_DIM + co + g * 8);
            uint2 lo; lo.x = v.x; lo.y = v.y;
            uint2 hi; hi.x = v.z; hi.y = v.w;
            *reinterpret_cast<uint2*>(&halo[(2 * g + 0) * PLANE_B + px * 8]) = lo;
            *reinterpret_cast<uint2*>(&halo[(2 * g + 1) * PLANE_B + px * 8]) = hi;
        }
    }

    // ---- own q (f16 pairs kept packed)
    unsigned int qreg[16];
    if (valid) {
        const uint4* qp = reinterpret_cast<const uint4*>(base + (size_t)s * QKV_C + co);
        #pragma unroll
        for (int g = 0; g < 4; ++g) {
            uint4 qg = qp[g];
            qreg[4 * g + 0] = qg.x; qreg[4 * g + 1] = qg.y;
            qreg[4 * g + 2] = qg.z; qreg[4 * g + 3] = qg.w;
        }
    }
    __syncthreads();

    // ---- QK: 49 dots from LDS via v_dot2_f32_f16
    float logits[49];
    if (valid) {
        #pragma unroll
        for (int di = 0; di < 7; ++di) {
            #pragma unroll
            for (int dj = 0; dj < 7; ++dj) {
                const int hp = (ty + di) * HALO + (tx + dj);
                const char* hb = halo + hp * 8;
                float acc0 = 0.f, acc1 = 0.f;
                #pragma unroll
                for (int pl = 0; pl < 8; ++pl) {
                    uint2 kk = *reinterpret_cast<const uint2*>(hb + pl * PLANE_B);
#if __has_builtin(__builtin_amdgcn_fdot2)
                    acc0 = __builtin_amdgcn_fdot2(
                        __builtin_bit_cast(f16x2, qreg[2 * pl]),
                        __builtin_bit_cast(f16x2, kk.x), acc0, false);
                    acc1 = __builtin_amdgcn_fdot2(
                        __builtin_bit_cast(f16x2, qreg[2 * pl + 1]),
                        __builtin_bit_cast(f16x2, kk.y), acc1, false);
#else
                    f16x2 qa = __builtin_bit_cast(f16x2, qreg[2 * pl]);
                    f16x2 qb = __builtin_bit_cast(f16x2, qreg[2 * pl + 1]);
                    f16x2 ka = __builtin_bit_cast(f16x2, kk.x);
                    f16x2 kb = __builtin_bit_cast(f16x2, kk.y);
                    acc0 += (float)qa[0] * (float)ka[0] + (float)qa[1] * (float)ka[1];
                    acc1 += (float)qb[0] * (float)kb[0] + (float)qb[1] * (float)kb[1];
#endif
                }
                logits[di * 7 + dj] = acc0 + acc1 + rel_bias[(nh * 7 + di) * 7 + dj];
            }
        }
    }
    __syncthreads();    // all K reads done before V overwrites

    // ---- stage V halo (bf16) into the same buffer
    #pragma unroll
    for (int i = 0; i < 8; ++i) {
        const int idx = tid + i * 256;
        if (idx < NPX * 4) {
            const int px = idx >> 2, g = idx & 3;
            const int hy = px / HALO, hx = px - hy * HALO;
            const int y = min(max(th0 - 3 + hy, 0), 55);
            const int x = min(max(tw0 - 3 + hx, 0), 55);
            const uint4 v = *reinterpret_cast<const uint4*>(
                base + (size_t)(y * IMG_W + x) * QKV_C + 2 * C_DIM + co + g * 8);
            uint2 lo; lo.x = v.x; lo.y = v.y;
            uint2 hi; hi.x = v.z; hi.y = v.w;
            *reinterpret_cast<uint2*>(&halo[(2 * g + 0) * PLANE_B + px * 8]) = lo;
            *reinterpret_cast<uint2*>(&halo[(2 * g + 1) * PLANE_B + px * 8]) = hi;
        }
    }

    // ---- softmax (overlaps V staging latency); pack p to bf16 pairs
    unsigned int ppk[25];
    float inv = 0.f;
    if (valid) {
        float mx = logits[0];
        #pragma unroll
        for (int i = 1; i < 49; ++i) mx = fmaxf(mx, logits[i]);
        float sum = 0.f;
        #pragma unroll
        for (int i = 0; i < 24; ++i) {
            float e0 = __expf(logits[2 * i] - mx);
            float e1 = __expf(logits[2 * i + 1] - mx);
            sum += e0 + e1;
            ppk[i] = f2bf_bits(e0) << 16 | f2bf_bits(e1);
        }
        {
            float e0 = __expf(logits[48] - mx);
            sum += e0;
            ppk[24] = f2bf_bits(e0) << 16;
        }
        inv = 1.f / sum;
    }
    __syncthreads();

    // ---- PV: accumulate o from LDS (bf16 unpack + pk_fma)
    if (valid) {
        f32x2 o2[16];
        #pragma unroll
        for (int p = 0; p < 16; ++p) o2[p] = f32x2{0.f, 0.f};

        #pragma unroll
        for (int n = 0; n < 49; ++n) {
            const unsigned int pu = ppk[n >> 1];
            const float pv = (n & 1) ? u2f(pu << 16) : u2f(pu & 0xFFFF0000u);
            const int di = n / 7, dj = n % 7;
            const int hp = (ty + di) * HALO + (tx + dj);
            const char* hb = halo + hp * 8;
            const f32x2 pp = f32x2{pv, pv};
            #pragma unroll
            for (int pl = 0; pl < 8; ++pl) {
                uint2 vv = *reinterpret_cast<const uint2*>(hb + pl * PLANE_B);
                f32x2 v0 = f32x2{u2f(vv.x << 16), u2f(vv.x & 0xFFFF0000u)};
                f32x2 v1 = f32x2{u2f(vv.y << 16), u2f(vv.y & 0xFFFF0000u)};
                o2[2 * pl]     += pp * v0;
                o2[2 * pl + 1] += pp * v1;
            }
        }

        uint4* dst = reinterpret_cast<uint4*>(outt + ((size_t)b * SP + s) * C_DIM + co);
        #pragma unroll
        for (int g = 0; g < 4; ++g) {
            uint4 pk;
            pk.x = f2bf_bits(o2[4 * g + 0].x * inv) | (f2bf_bits(o2[4 * g + 0].y * inv) << 16);
            pk.y = f2bf_bits(o2[4 * g + 1].x * inv) | (f2bf_bits(o2[4 * g + 1].y * inv) << 16);
            pk.z = f2bf_bits(o2[4 * g + 2].x * inv) | (f2bf_bits(o2[4 * g + 2].y * inv) << 16);
            pk.w = f2bf_bits(o2[4 * g + 3].x * inv) | (f2bf_bits(o2[4 * g + 3].y * inv) << 16);
            dst[g] = pk;
        }
    }
}

// ---------------------------------------------------------------------------
extern "C" void kernel_launch(void* const* d_in, const int* in_sizes, int n_in,
                              void* d_out, int out_size, void* d_ws, size_t ws_size,
                              hipStream_t stream) {
    const float* x        = (const float*)d_in[0];
    const float* w_qkv    = (const float*)d_in[1];
    const float* b_qkv    = (const float*)d_in[2];
    const float* w_proj   = (const float*)d_in[3];
    const float* b_proj   = (const float*)d_in[4];
    const float* rel_bias = (const float*)d_in[5];
    float* out = (float*)d_out;

    __hip_bfloat16* xt   = (__hip_bfloat16*)d_ws;
    __hip_bfloat16* wq   = xt + (size_t)4 * SP * C_DIM;
    __hip_bfloat16* wp   = wq + (size_t)QKV_C * C_DIM;
    __hip_bfloat16* qkvt = wp + (size_t)C_DIM * C_DIM;
    __hip_bfloat16* att  = qkvt + (size_t)4 * SP * QKV_C;

    const float scale = 0.17677669529663687f;  // 32^-0.5
    const int nwq = QKV_C * C_DIM, nwp = C_DIM * C_DIM;

    convert_w2_kernel<<<dim3((nwq + nwp + 255) / 256), 256, 0, stream>>>(
        w_qkv, nwq, wq, w_proj, nwp, wp);
    transpose_convert_kernel<<<dim3(98, 12, 4), dim3(256), 0, stream>>>(x, xt);

    // qkv projection: O=1152, K=384 -> [b][SP][1152], q/k f16, v bf16
    gemm_bf16_mfma<true, __hip_bfloat16><<<dim3(25, 9, 4), 256, 0, stream>>>(
        wq, xt, b_qkv, qkvt, QKV_C, C_DIM, scale, C_DIM, F16_ROWS);

    // attention: 4 b * 12 heads * 16 tiles (4x4 of 16x16 px)
    na_attn_kernel<<<dim3(4 * NH_DIM * 16), 256, 0, stream>>>(qkvt, rel_bias, att);

    // output projection: O=384, K=384, fp32 output [b][384][S_HW]
    gemm_bf16_mfma<false, float><<<dim3(25, 3, 4), 256, 0, stream>>>(
        wp, att, b_proj, out, C_DIM, C_DIM, 1.f, 0, 0);
}

// Round 6
// 97.392 us; speedup vs baseline: 7.6544x; 1.0424x over previous
//
#include <hip/hip_runtime.h>
#include <hip/hip_bf16.h>
#include <hip/hip_fp16.h>

// B=4, C=384, H=W=56 (S=3136, padded 3200), NH=12, HD=32, WS=7, pad=3.
#define S_HW 3136
#define SP   3200
#define IMG_W 56
#define C_DIM 384
#define NH_DIM 12
#define QKV_C 1152

// attention tiling
#define TB 16              // tile is TB x TB pixels
#define HALO 22            // TB + 6
#define NPX 484            // HALO*HALO
#define PLANE_B 3880       // NPX*8 rounded up (+8) to stagger plane banks

typedef float f32x4 __attribute__((ext_vector_type(4)));
typedef float f32x2 __attribute__((ext_vector_type(2)));
typedef short bf16x8 __attribute__((ext_vector_type(8)));
typedef _Float16 f16x2 __attribute__((ext_vector_type(2)));

__device__ __forceinline__ void gld_lds16(const void* g, void* lds) {
    __builtin_amdgcn_global_load_lds(
        (const __attribute__((address_space(1))) void*)g,
        (__attribute__((address_space(3))) void*)lds, 16, 0, 0);
}

__device__ __forceinline__ float u2f(unsigned int u) { return __uint_as_float(u); }
__device__ __forceinline__ unsigned int f2bf_bits(float f) {
    unsigned int u = __float_as_uint(f);
    u += 0x7FFF + ((u >> 16) & 1);   // round-nearest-even
    return u >> 16;
}
__device__ __forceinline__ unsigned int f2h_bits(float f) {
    return (unsigned int)__half_as_ushort(__float2half(f));
}

// ---------------------------------------------------------------------------
// fp32 -> bf16 convert for both weight tensors in one launch
// ---------------------------------------------------------------------------
__global__ __launch_bounds__(256) void convert_w2_kernel(
    const float* __restrict__ a, int na, __hip_bfloat16* __restrict__ oa,
    const float* __restrict__ b, int nb, __hip_bfloat16* __restrict__ ob)
{
    int i = blockIdx.x * 256 + threadIdx.x;
    if (i < na) oa[i] = __float2bfloat16(a[i]);
    else if (i < na + nb) ob[i - na] = __float2bfloat16(b[i - na]);
}

// ---------------------------------------------------------------------------
// x [4][384][3136] f32  ->  x_t [4][3200][384] bf16 (transpose + convert)
// ---------------------------------------------------------------------------
__global__ __launch_bounds__(256) void transpose_convert_kernel(
    const float* __restrict__ x, __hip_bfloat16* __restrict__ xt)
{
    __shared__ float t[32][33];
    const int b = blockIdx.z;
    const int c0 = blockIdx.y * 32, s0 = blockIdx.x * 32;
    const int tid = threadIdx.x;

    const int lc = tid >> 3, ls = (tid & 7) * 4;
    float4 v = *reinterpret_cast<const float4*>(
        &x[((size_t)b * C_DIM + c0 + lc) * S_HW + s0 + ls]);
    t[lc][ls + 0] = v.x; t[lc][ls + 1] = v.y;
    t[lc][ls + 2] = v.z; t[lc][ls + 3] = v.w;
    __syncthreads();

    const int ws = tid >> 3, wc = (tid & 7) * 4;
    uint2 pk;
    pk.x = f2bf_bits(t[wc + 0][ws]) | (f2bf_bits(t[wc + 1][ws]) << 16);
    pk.y = f2bf_bits(t[wc + 2][ws]) | (f2bf_bits(t[wc + 3][ws]) << 16);
    *reinterpret_cast<uint2*>(
        &xt[((size_t)b * SP + s0 + ws) * C_DIM + c0 + wc]) = pk;
}

// ---------------------------------------------------------------------------
// bf16 MFMA GEMM (m97 structure), tile 128 x (NF*32), BK=32, 4 waves (2x2).
// TRANS_OUT=true : Y [b][SP][O] f16 (qkv output, channel-contiguous)
// TRANS_OUT=false: Y fp32 [b][O][S_HW]  (proj output)
// ---------------------------------------------------------------------------
template <bool TRANS_OUT, int NF, typename OutT>
__global__ __launch_bounds__(256) void gemm_bf16_mfma(
    const __hip_bfloat16* __restrict__ A,    // [O][K]
    const __hip_bfloat16* __restrict__ Bt,   // [batch][SP][K]
    const float* __restrict__ bias,
    OutT* __restrict__ Y,
    int O, int K, float qscale, int qrows)
{
    constexpr int BN = NF * 32;
    __shared__ char smem[8192 + BN * 64];
    char* As = smem;             // [128][32] bf16 linear
    char* Bs = smem + 8192;      // [BN][32] bf16 linear

    const int b   = blockIdx.z;
    const int m0  = blockIdx.y * 128;
    const int n0  = blockIdx.x * BN;
    const int tid = threadIdx.x;
    const int w = tid >> 6, l = tid & 63;
    const int wr = w >> 1, wc = w & 1;

    const int srow = l >> 2;          // staging: row within 16-row chunk
    const int skk  = (l & 3) * 8;     // staging: k element offset

    const __hip_bfloat16* Bb = Bt + (size_t)b * SP * K;

    f32x4 acc[4][NF];
    #pragma unroll
    for (int i = 0; i < 4; ++i)
        #pragma unroll
        for (int j = 0; j < NF; ++j) {
            f32x4 z = {0.f, 0.f, 0.f, 0.f};
            acc[i][j] = z;
        }

    const int frow = l & 15;
    const int fk   = (l >> 4) * 16;   // byte offset of 8-bf16 k-group

    for (int k0 = 0; k0 < K; k0 += 32) {
        #pragma unroll
        for (int j = 0; j < 2; ++j) {
            const int chunk = w * 2 + j;           // wave-uniform
            const int m = chunk * 16 + srow;
            gld_lds16(A + (size_t)(m0 + m) * K + k0 + skk, As + chunk * 1024);
        }
        if (NF == 4) {
            #pragma unroll
            for (int j = 0; j < 2; ++j) {
                const int chunk = w * 2 + j;
                const int m = chunk * 16 + srow;
                gld_lds16(Bb + (size_t)(n0 + m) * K + k0 + skk, Bs + chunk * 1024);
            }
        } else {
            const int m = w * 16 + srow;
            gld_lds16(Bb + (size_t)(n0 + m) * K + k0 + skk, Bs + w * 1024);
        }
        __syncthreads();
        bf16x8 af[4], bfr[NF];
        #pragma unroll
        for (int mi = 0; mi < 4; ++mi)
            af[mi] = *reinterpret_cast<const bf16x8*>(
                As + (wr * 64 + mi * 16 + frow) * 64 + fk);
        #pragma unroll
        for (int ni = 0; ni < NF; ++ni)
            bfr[ni] = *reinterpret_cast<const bf16x8*>(
                Bs + (wc * (NF * 16) + ni * 16 + frow) * 64 + fk);
        #pragma unroll
        for (int mi = 0; mi < 4; ++mi)
            #pragma unroll
            for (int ni = 0; ni < NF; ++ni)
                acc[mi][ni] = __builtin_amdgcn_mfma_f32_16x16x32_bf16(
                    af[mi], bfr[ni], acc[mi][ni], 0, 0, 0);
        __syncthreads();
    }

    // epilogue: C/D layout col=lane&15, row=(lane>>4)*4+reg  [m89]
    const int crow0 = (l >> 4) * 4;
    const int ccol  = l & 15;
    if (TRANS_OUT) {
        // Y[b][col][row] f16; per (mi,ni) one 8B store of 4 consecutive rows
        __hip_bfloat16* Yb = (__hip_bfloat16*)Y + (size_t)b * SP * O;
        #pragma unroll
        for (int ni = 0; ni < NF; ++ni) {
            const int col = n0 + wc * (NF * 16) + ni * 16 + ccol;
            if (col >= S_HW) continue;
            #pragma unroll
            for (int mi = 0; mi < 4; ++mi) {
                const int row0 = m0 + wr * 64 + mi * 16 + crow0;
                const float sc = (row0 < qrows) ? qscale : 1.f;
                float v0 = (acc[mi][ni][0] + bias[row0 + 0]) * sc;
                float v1 = (acc[mi][ni][1] + bias[row0 + 1]) * sc;
                float v2 = (acc[mi][ni][2] + bias[row0 + 2]) * sc;
                float v3 = (acc[mi][ni][3] + bias[row0 + 3]) * sc;
                uint2 pk;
                pk.x = f2h_bits(v0) | (f2h_bits(v1) << 16);
                pk.y = f2h_bits(v2) | (f2h_bits(v3) << 16);
                *reinterpret_cast<uint2*>(&Yb[(size_t)col * O + row0]) = pk;
            }
        }
    } else {
        float* Yb = (float*)Y + (size_t)b * O * S_HW;
        #pragma unroll
        for (int ni = 0; ni < NF; ++ni) {
            const int col = n0 + wc * (NF * 16) + ni * 16 + ccol;
            if (col >= S_HW) continue;
            #pragma unroll
            for (int mi = 0; mi < 4; ++mi) {
                #pragma unroll
                for (int r = 0; r < 4; ++r) {
                    const int row = m0 + wr * 64 + mi * 16 + crow0 + r;
                    float v = acc[mi][ni][r] + bias[row];
                    if (row < qrows) v *= qscale;
                    Yb[(size_t)row * S_HW + col] = v;
                }
            }
        }
    }
}

// ---------------------------------------------------------------------------
// Neighborhood attention, LDS-staged halo. q/k/v all f16.
// QK via v_dot2_f32_f16; PV via v_fma_mix_f32 (f16 source, f32 accumulate).
// ---------------------------------------------------------------------------
__global__ __launch_bounds__(256, 4) void na_attn_kernel(
    const __hip_bfloat16* __restrict__ qkvt, const float* __restrict__ rel_bias,
    __hip_bfloat16* __restrict__ outt)
{
    __shared__ alignas(16) char halo[8 * PLANE_B];   // ~31 KB

    const int blk  = blockIdx.x;          // b*NH*16 + nh*16 + tile
    const int tile = blk & 15;
    const int bn   = blk >> 4;
    const int nh   = bn % NH_DIM;
    const int b    = bn / NH_DIM;
    const int th0  = (tile >> 2) * TB;
    const int tw0  = (tile & 3) * TB;

    const int tid = threadIdx.x;
    const int ty = tid >> 4, tx = tid & 15;
    const int h = th0 + ty, w = tw0 + tx;
    const bool valid = (h < 56) && (w < 56);
    const int s = h * IMG_W + w;

    const __hip_bfloat16* base = qkvt + (size_t)b * SP * QKV_C;
    const int co = nh * 32;

    // ---- stage K halo (f16 bits; staging is bit-agnostic)
    #pragma unroll
    for (int i = 0; i < 8; ++i) {
        const int idx = tid + i * 256;
        if (idx < NPX * 4) {
            const int px = idx >> 2, g = idx & 3;
            const int hy = px / HALO, hx = px - hy * HALO;
            const int y = min(max(th0 - 3 + hy, 0), 55);
            const int x = min(max(tw0 - 3 + hx, 0), 55);
            const uint4 v = *reinterpret_cast<const uint4*>(
                base + (size_t)(y * IMG_W + x) * QKV_C + C_DIM + co + g * 8);
            uint2 lo; lo.x = v.x; lo.y = v.y;
            uint2 hi; hi.x = v.z; hi.y = v.w;
            *reinterpret_cast<uint2*>(&halo[(2 * g + 0) * PLANE_B + px * 8]) = lo;
            *reinterpret_cast<uint2*>(&halo[(2 * g + 1) * PLANE_B + px * 8]) = hi;
        }
    }

    // ---- own q (f16 pairs kept packed)
    unsigned int qreg[16];
    if (valid) {
        const uint4* qp = reinterpret_cast<const uint4*>(base + (size_t)s * QKV_C + co);
        #pragma unroll
        for (int g = 0; g < 4; ++g) {
            uint4 qg = qp[g];
            qreg[4 * g + 0] = qg.x; qreg[4 * g + 1] = qg.y;
            qreg[4 * g + 2] = qg.z; qreg[4 * g + 3] = qg.w;
        }
    }
    __syncthreads();

    // ---- QK: 49 dots from LDS via v_dot2_f32_f16
    float logits[49];
    if (valid) {
        #pragma unroll
        for (int di = 0; di < 7; ++di) {
            #pragma unroll
            for (int dj = 0; dj < 7; ++dj) {
                const int hp = (ty + di) * HALO + (tx + dj);
                const char* hb = halo + hp * 8;
                float acc0 = 0.f, acc1 = 0.f;
                #pragma unroll
                for (int pl = 0; pl < 8; ++pl) {
                    uint2 kk = *reinterpret_cast<const uint2*>(hb + pl * PLANE_B);
#if __has_builtin(__builtin_amdgcn_fdot2)
                    acc0 = __builtin_amdgcn_fdot2(
                        __builtin_bit_cast(f16x2, qreg[2 * pl]),
                        __builtin_bit_cast(f16x2, kk.x), acc0, false);
                    acc1 = __builtin_amdgcn_fdot2(
                        __builtin_bit_cast(f16x2, qreg[2 * pl + 1]),
                        __builtin_bit_cast(f16x2, kk.y), acc1, false);
#else
                    f16x2 qa = __builtin_bit_cast(f16x2, qreg[2 * pl]);
                    f16x2 qb = __builtin_bit_cast(f16x2, qreg[2 * pl + 1]);
                    f16x2 ka = __builtin_bit_cast(f16x2, kk.x);
                    f16x2 kb = __builtin_bit_cast(f16x2, kk.y);
                    acc0 += (float)qa[0] * (float)ka[0] + (float)qa[1] * (float)ka[1];
                    acc1 += (float)qb[0] * (float)kb[0] + (float)qb[1] * (float)kb[1];
#endif
                }
                logits[di * 7 + dj] = acc0 + acc1 + rel_bias[(nh * 7 + di) * 7 + dj];
            }
        }
    }
    __syncthreads();    // all K reads done before V overwrites

    // ---- stage V halo (f16) into the same buffer
    #pragma unroll
    for (int i = 0; i < 8; ++i) {
        const int idx = tid + i * 256;
        if (idx < NPX * 4) {
            const int px = idx >> 2, g = idx & 3;
            const int hy = px / HALO, hx = px - hy * HALO;
            const int y = min(max(th0 - 3 + hy, 0), 55);
            const int x = min(max(tw0 - 3 + hx, 0), 55);
            const uint4 v = *reinterpret_cast<const uint4*>(
                base + (size_t)(y * IMG_W + x) * QKV_C + 2 * C_DIM + co + g * 8);
            uint2 lo; lo.x = v.x; lo.y = v.y;
            uint2 hi; hi.x = v.z; hi.y = v.w;
            *reinterpret_cast<uint2*>(&halo[(2 * g + 0) * PLANE_B + px * 8]) = lo;
            *reinterpret_cast<uint2*>(&halo[(2 * g + 1) * PLANE_B + px * 8]) = hi;
        }
    }

    // ---- softmax (overlaps V staging latency); pack p to bf16 pairs
    unsigned int ppk[25];
    float inv = 0.f;
    if (valid) {
        float mx = logits[0];
        #pragma unroll
        for (int i = 1; i < 49; ++i) mx = fmaxf(mx, logits[i]);
        float sum = 0.f;
        #pragma unroll
        for (int i = 0; i < 24; ++i) {
            float e0 = __expf(logits[2 * i] - mx);
            float e1 = __expf(logits[2 * i + 1] - mx);
            sum += e0 + e1;
            ppk[i] = f2bf_bits(e0) << 16 | f2bf_bits(e1);
        }
        {
            float e0 = __expf(logits[48] - mx);
            sum += e0;
            ppk[24] = f2bf_bits(e0) << 16;
        }
        inv = 1.f / sum;
    }
    __syncthreads();

    // ---- PV: accumulate o from LDS via fma_mix (f16 v, f32 accum)
    if (valid) {
        float o[32];
        #pragma unroll
        for (int c = 0; c < 32; ++c) o[c] = 0.f;

        #pragma unroll
        for (int n = 0; n < 49; ++n) {
            const unsigned int pu = ppk[n >> 1];
            const float pv = (n & 1) ? u2f(pu << 16) : u2f(pu & 0xFFFF0000u);
            const int di = n / 7, dj = n % 7;
            const int hp = (ty + di) * HALO + (tx + dj);
            const char* hb = halo + hp * 8;
            #pragma unroll
            for (int pl = 0; pl < 8; ++pl) {
                uint2 vv = *reinterpret_cast<const uint2*>(hb + pl * PLANE_B);
                f16x2 va = __builtin_bit_cast(f16x2, vv.x);
                f16x2 vb = __builtin_bit_cast(f16x2, vv.y);
                o[4 * pl + 0] = fmaf((float)va[0], pv, o[4 * pl + 0]);
                o[4 * pl + 1] = fmaf((float)va[1], pv, o[4 * pl + 1]);
                o[4 * pl + 2] = fmaf((float)vb[0], pv, o[4 * pl + 2]);
                o[4 * pl + 3] = fmaf((float)vb[1], pv, o[4 * pl + 3]);
            }
        }

        uint4* dst = reinterpret_cast<uint4*>(outt + ((size_t)b * SP + s) * C_DIM + co);
        #pragma unroll
        for (int g = 0; g < 4; ++g) {
            uint4 pk;
            pk.x = f2bf_bits(o[8 * g + 0] * inv) | (f2bf_bits(o[8 * g + 1] * inv) << 16);
            pk.y = f2bf_bits(o[8 * g + 2] * inv) | (f2bf_bits(o[8 * g + 3] * inv) << 16);
            pk.z = f2bf_bits(o[8 * g + 4] * inv) | (f2bf_bits(o[8 * g + 5] * inv) << 16);
            pk.w = f2bf_bits(o[8 * g + 6] * inv) | (f2bf_bits(o[8 * g + 7] * inv) << 16);
            dst[g] = pk;
        }
    }
}

// ---------------------------------------------------------------------------
extern "C" void kernel_launch(void* const* d_in, const int* in_sizes, int n_in,
                              void* d_out, int out_size, void* d_ws, size_t ws_size,
                              hipStream_t stream) {
    const float* x        = (const float*)d_in[0];
    const float* w_qkv    = (const float*)d_in[1];
    const float* b_qkv    = (const float*)d_in[2];
    const float* w_proj   = (const float*)d_in[3];
    const float* b_proj   = (const float*)d_in[4];
    const float* rel_bias = (const float*)d_in[5];
    float* out = (float*)d_out;

    __hip_bfloat16* xt   = (__hip_bfloat16*)d_ws;
    __hip_bfloat16* wq   = xt + (size_t)4 * SP * C_DIM;
    __hip_bfloat16* wp   = wq + (size_t)QKV_C * C_DIM;
    __hip_bfloat16* qkvt = wp + (size_t)C_DIM * C_DIM;
    __hip_bfloat16* att  = qkvt + (size_t)4 * SP * QKV_C;

    const float scale = 0.17677669529663687f;  // 32^-0.5
    const int nwq = QKV_C * C_DIM, nwp = C_DIM * C_DIM;

    convert_w2_kernel<<<dim3((nwq + nwp + 255) / 256), 256, 0, stream>>>(
        w_qkv, nwq, wq, w_proj, nwp, wp);
    transpose_convert_kernel<<<dim3(98, 12, 4), dim3(256), 0, stream>>>(x, xt);

    // qkv projection: O=1152, K=384 -> [b][SP][1152] f16 (q pre-scaled)
    gemm_bf16_mfma<true, 4, __hip_bfloat16><<<dim3(25, 9, 4), 256, 0, stream>>>(
        wq, xt, b_qkv, qkvt, QKV_C, C_DIM, scale, C_DIM);

    // attention: 4 b * 12 heads * 16 tiles (4x4 of 16x16 px)
    na_attn_kernel<<<dim3(4 * NH_DIM * 16), 256, 0, stream>>>(qkvt, rel_bias, att);

    // output projection: O=384, K=384, tile 128x64 -> 600 blocks, fp32 out
    gemm_bf16_mfma<false, 2, float><<<dim3(50, 3, 4), 256, 0, stream>>>(
        wp, att, b_proj, out, C_DIM, C_DIM, 1.f, 0);
}